// Round 1
// baseline (527.526 us; speedup 1.0000x reference)
//
#include <hip/hip_runtime.h>

// Composite filters: second-level DWT (db2) applied to the hi branch of the
// first-level DWT collapses into one 10-tap stride-4 conv along channels.
struct Gs { float g0[10]; float g1[10]; };

__host__ __device__ constexpr Gs make_g() {
  double H0[4] = {0.48296291314469025, 0.836516303737469,
                  0.22414386804185735, -0.12940952255092145};
  double H1[4] = {0.12940952255092145, -0.22414386804185735,
                  0.836516303737469, -0.48296291314469025};
  Gs r{};
  for (int d = 0; d < 10; ++d) {
    double a = 0.0, b = 0.0;
    for (int k = 0; k < 4; ++k) {
      int j = d - 2 * k;
      if (j >= 0 && j < 4) { a += H0[k] * H1[j]; b += H1[k] * H1[j]; }
    }
    r.g0[d] = (float)a; r.g1[d] = (float)b;
  }
  return r;
}

// Kernel A: A[b][c][s] (c in [0,180), s = h*64+w in [0,4096)) where
//   c in [0,90):    A = sum_d G0[d] * x[b][4c+d-6][s]   (zero-pad c<0)
//   c in [90,180):  A = sum_d G1[d] * x[b][4(c-90)+d-6][s]
// Grid: 16(b) * 16(s-blocks of 256) * 4(channel segments) = 1024 blocks.
__global__ __launch_bounds__(256) void dwt2_kernel(const float* __restrict__ x,
                                                   float* __restrict__ A) {
  constexpr Gs G = make_g();
  const int bx  = blockIdx.x;
  const int seg = bx & 3;
  const int pb  = bx >> 2;        // 0..255
  const int b   = pb >> 4;        // 0..15
  const int s   = ((pb & 15) << 8) + threadIdx.x;  // 0..4095

  const float* xb = x + (size_t)b * 360 * 4096 + s;
  float*       Ab = A + (size_t)b * 180 * 4096 + s;

  const int c0 = (seg * 90) >> 2;        // 0,22,45,67
  const int c1 = ((seg + 1) * 90) >> 2;  // 22,45,67,90

  float w[10];
  const int base = 4 * c0 - 6;
#pragma unroll
  for (int i = 0; i < 10; ++i) {
    int idx = base + i;
    w[i] = (idx >= 0) ? xb[(size_t)idx * 4096] : 0.0f;
  }

  for (int c = c0; c < c1; ++c) {
    float lo = 0.0f, hi = 0.0f;
#pragma unroll
    for (int d = 0; d < 10; ++d) {
      lo = fmaf(G.g0[d], w[d], lo);
      hi = fmaf(G.g1[d], w[d], hi);
    }
    Ab[(size_t)c * 4096]        = lo;
    Ab[(size_t)(c + 90) * 4096] = hi;
#pragma unroll
    for (int i = 0; i < 6; ++i) w[i] = w[i + 4];
    if (c + 1 < c1) {
      const int nb = 4 * c + 4;  // max 4*88+7 = 359 < 360
#pragma unroll
      for (int i = 0; i < 4; ++i) w[6 + i] = xb[(size_t)(nb + i) * 4096];
    }
  }
}

// Kernel B: per contiguous 180-float group n (65536 total):
//   y[j]  = relu(cb + sum_{r<2,k<7} in[r*90 + j+k-3] * cw[r][k])   (j in [0,90))
//   h[o]  = relu(b1[o] + sum_k y[k]*w1[o][k])                      (o in [0,128))
//   out[o]= b2[o] + sum_k h[k]*w2[o][k]                            (o in [0,256))
// 16 groups per 256-thread block. Thread map for FCs: g = tid&15, olo = tid>>4,
// so each weight element broadcasts across 16 consecutive lanes.
#define GPB 16
__global__ __launch_bounds__(256) void mlp_kernel(
    const float* __restrict__ A,
    const float* __restrict__ cw, const float* __restrict__ cb,
    const float* __restrict__ w1, const float* __restrict__ b1,
    const float* __restrict__ w2, const float* __restrict__ b2,
    float* __restrict__ out) {
  __shared__ float s_io[GPB * 256];   // input (16*180) then output staging (16*256)
  __shared__ float s_y[GPB][92];      // 90 + pad (stride 92: 2-way bank alias = free)
  __shared__ float s_h[GPB][132];     // 128 + pad (16B-aligned rows, 2-way alias)

  const int tid = threadIdx.x;
  const size_t nb = blockIdx.x;       // 4096 blocks

  // ---- load 16 groups (contiguous 2880 floats) ----
  const float* src = A + nb * (GPB * 180);
  for (int i = tid; i < GPB * 180; i += 256) s_io[i] = src[i];
  __syncthreads();

  // ---- conv (2x7, pad 3) + bias + relu ----
  float cwr[2][7];
#pragma unroll
  for (int r = 0; r < 2; ++r)
#pragma unroll
    for (int k = 0; k < 7; ++k) cwr[r][k] = cw[r * 7 + k];
  const float cbv = cb[0];

  for (int o = tid; o < GPB * 90; o += 256) {
    const int g = o / 90, j = o % 90;
    float acc = cbv;
#pragma unroll
    for (int r = 0; r < 2; ++r)
#pragma unroll
      for (int k = 0; k < 7; ++k) {
        const int m = j + k - 3;
        if (m >= 0 && m < 90) acc = fmaf(s_io[g * 180 + r * 90 + m], cwr[r][k], acc);
      }
    s_y[g][j] = fmaxf(acc, 0.0f);
  }
  __syncthreads();

  const int g = tid & 15, olo = tid >> 4;

  // ---- fc1: 90 -> 128, relu ----
  {
    float acc[8];
#pragma unroll
    for (int i = 0; i < 8; ++i) acc[i] = b1[olo + 16 * i];
    const float2* w1v = (const float2*)w1;  // row o = 45 float2, rows 8B-aligned
    for (int k2 = 0; k2 < 45; ++k2) {
      const float2 yv = *(const float2*)&s_y[g][2 * k2];
#pragma unroll
      for (int i = 0; i < 8; ++i) {
        const float2 wv = w1v[(size_t)(olo + 16 * i) * 45 + k2];
        acc[i] = fmaf(yv.x, wv.x, acc[i]);
        acc[i] = fmaf(yv.y, wv.y, acc[i]);
      }
    }
#pragma unroll
    for (int i = 0; i < 8; ++i) s_h[g][olo + 16 * i] = fmaxf(acc[i], 0.0f);
  }
  __syncthreads();

  // ---- fc2: 128 -> 256 ----
  {
    float acc[16];
#pragma unroll
    for (int i = 0; i < 16; ++i) acc[i] = b2[olo + 16 * i];
    const float4* w2v = (const float4*)w2;  // row o = 32 float4, 16B-aligned
    for (int k4 = 0; k4 < 32; ++k4) {
      const float4 hv = *(const float4*)&s_h[g][4 * k4];
#pragma unroll
      for (int i = 0; i < 16; ++i) {
        const float4 wv = w2v[(size_t)(olo + 16 * i) * 32 + k4];
        acc[i] = fmaf(hv.x, wv.x, acc[i]);
        acc[i] = fmaf(hv.y, wv.y, acc[i]);
        acc[i] = fmaf(hv.z, wv.z, acc[i]);
        acc[i] = fmaf(hv.w, wv.w, acc[i]);
      }
    }
#pragma unroll
    for (int i = 0; i < 16; ++i) s_io[g * 256 + olo + 16 * i] = acc[i];
  }
  __syncthreads();

  // ---- coalesced write-out (4096 contiguous floats) ----
  float* dst = out + nb * (GPB * 256);
  for (int i = tid; i < GPB * 256; i += 256) dst[i] = s_io[i];
}

extern "C" void kernel_launch(void* const* d_in, const int* in_sizes, int n_in,
                              void* d_out, int out_size, void* d_ws, size_t ws_size,
                              hipStream_t stream) {
  const float* x  = (const float*)d_in[0];
  const float* cw = (const float*)d_in[1];
  const float* cb = (const float*)d_in[2];
  const float* w1 = (const float*)d_in[3];
  const float* b1 = (const float*)d_in[4];
  const float* w2 = (const float*)d_in[5];
  const float* b2 = (const float*)d_in[6];
  float* outp = (float*)d_out;
  float* A = (float*)d_ws;  // 16*180*4096 floats = 47.2 MB

  dwt2_kernel<<<1024, 256, 0, stream>>>(x, A);
  mlp_kernel<<<4096, 256, 0, stream>>>(A, cw, cb, w1, b1, w2, b2, outp);
}

// Round 2
// 324.100 us; speedup vs baseline: 1.6277x; 1.6277x over previous
//
#include <hip/hip_runtime.h>

// Composite filters: second-level DWT (db2) applied to the hi branch of the
// first-level DWT collapses into one 10-tap stride-4 conv along channels.
struct Gs { float g0[10]; float g1[10]; };

__host__ __device__ constexpr Gs make_g() {
  double H0[4] = {0.48296291314469025, 0.836516303737469,
                  0.22414386804185735, -0.12940952255092145};
  double H1[4] = {0.12940952255092145, -0.22414386804185735,
                  0.836516303737469, -0.48296291314469025};
  Gs r{};
  for (int d = 0; d < 10; ++d) {
    double a = 0.0, b = 0.0;
    for (int k = 0; k < 4; ++k) {
      int j = d - 2 * k;
      if (j >= 0 && j < 4) { a += H0[k] * H1[j]; b += H1[k] * H1[j]; }
    }
    r.g0[d] = (float)a; r.g1[d] = (float)b;
  }
  return r;
}

// ---------------------------------------------------------------------------
// Kernel A v2: A[b][c][s] composite 10-tap stride-4 conv along channels.
// float2 per thread (s-chunk of 512 px), 8 channel segments -> 1024 blocks.
__global__ __launch_bounds__(256) void dwt2_kernel(const float* __restrict__ x,
                                                   float* __restrict__ A) {
  constexpr Gs G = make_g();
  const int bx    = blockIdx.x;
  const int seg   = bx & 7;
  const int pb    = bx >> 3;      // 0..127
  const int b     = pb >> 3;      // 0..15
  const int chunk = pb & 7;       // 0..7
  const int s     = chunk * 512 + 2 * threadIdx.x;

  const float2* xb = (const float2*)(x + (size_t)b * 360 * 4096 + s);
  float2*       Ab = (float2*)(A + (size_t)b * 180 * 4096 + s);
  // channel stride in float2 units: 2048

  const int c0 = (seg * 90) >> 3;
  const int c1 = ((seg + 1) * 90) >> 3;

  float2 w[10];
  const int base = 4 * c0 - 6;
#pragma unroll
  for (int i = 0; i < 10; ++i) {
    int idx = base + i;
    w[i] = (idx >= 0) ? xb[(size_t)idx * 2048] : float2{0.f, 0.f};
  }

  for (int c = c0; c < c1; ++c) {
    float2 nx[4];
    const bool pf = (c + 1 < c1);
    const int nb = 4 * c + 4;  // max 359
#pragma unroll
    for (int i = 0; i < 4; ++i)
      nx[i] = pf ? xb[(size_t)(nb + i) * 2048] : float2{0.f, 0.f};

    float2 lo{0.f, 0.f}, hi{0.f, 0.f};
#pragma unroll
    for (int d = 0; d < 10; ++d) {
      lo.x = fmaf(G.g0[d], w[d].x, lo.x);
      lo.y = fmaf(G.g0[d], w[d].y, lo.y);
      hi.x = fmaf(G.g1[d], w[d].x, hi.x);
      hi.y = fmaf(G.g1[d], w[d].y, hi.y);
    }
    Ab[(size_t)c * 2048]        = lo;
    Ab[(size_t)(c + 90) * 2048] = hi;
#pragma unroll
    for (int i = 0; i < 6; ++i) w[i] = w[i + 4];
#pragma unroll
    for (int i = 0; i < 4; ++i) w[6 + i] = nx[i];
  }
}

// ---------------------------------------------------------------------------
// Kernel B: conv(2x7,pad3)+relu then fc1 (90->128)+relu, weights-stationary.
// Grid: 256 blocks x 512 threads; each block: w1^T in LDS once, 4 chunks of
// 64 groups. Output H transposed: HT[o=128][n=65536].
__global__ __launch_bounds__(512) void conv_fc1_kernel(
    const float* __restrict__ A,
    const float* __restrict__ cw, const float* __restrict__ cb,
    const float* __restrict__ w1, const float* __restrict__ b1,
    float* __restrict__ HT) {
  __shared__ float w1T[90][132];   // 47,520 B (row stride 528 B, 16B aligned)
  __shared__ float b1s[128];
  __shared__ float As[64 * 180];   // 46,080 B
  __shared__ float Ys[90][68];     // 24,480 B (row stride 272 B)

  const int tid = threadIdx.x;

  // one-time: transpose w1 into LDS (coalesced global read)
  for (int i = tid; i < 128 * 90; i += 512) {
    int o = i / 90, k = i % 90;
    w1T[k][o] = w1[i];
  }
  if (tid < 128) b1s[tid] = b1[tid];

  const int to = tid & 31, tn = tid >> 5;  // o0 = 4*to, n0 = 4*tn
  const int o0 = 4 * to, n0 = 4 * tn;

  for (int it = 0; it < 4; ++it) {
    const int ch = blockIdx.x * 4 + it;     // 0..1023
    const size_t g0 = (size_t)ch * 64;

    __syncthreads();  // protect As/Ys reuse (and w1T on first pass)

    // stage 64 groups (contiguous flat)
    const float* src = A + g0 * 180;
    for (int i = tid; i < 64 * 180; i += 512) As[i] = src[i];
    __syncthreads();

    // conv: y[j][g]
    {
      float cwr[2][7];
#pragma unroll
      for (int r = 0; r < 2; ++r)
#pragma unroll
        for (int k = 0; k < 7; ++k) cwr[r][k] = cw[r * 7 + k];
      const float cbv = cb[0];
      for (int i = tid; i < 90 * 64; i += 512) {
        const int g = i & 63, j = i >> 6;
        float acc = cbv;
#pragma unroll
        for (int r = 0; r < 2; ++r)
#pragma unroll
          for (int k = 0; k < 7; ++k) {
            const int m = j + k - 3;
            if (m >= 0 && m < 90)
              acc = fmaf(As[g * 180 + r * 90 + m], cwr[r][k], acc);
          }
        Ys[j][g] = fmaxf(acc, 0.0f);
      }
    }
    __syncthreads();

    // fc1 GEMM: M=128(o) x N=64(g), K=90. 4x4 tile per thread.
    float acc[4][4];
#pragma unroll
    for (int a = 0; a < 4; ++a)
#pragma unroll
      for (int c = 0; c < 4; ++c) acc[a][c] = 0.0f;

#pragma unroll 2
    for (int k = 0; k < 90; ++k) {
      const float4 wv = *(const float4*)&w1T[k][o0];
      const float4 yv = *(const float4*)&Ys[k][n0];
      const float wq[4] = {wv.x, wv.y, wv.z, wv.w};
      const float yq[4] = {yv.x, yv.y, yv.z, yv.w};
#pragma unroll
      for (int a = 0; a < 4; ++a)
#pragma unroll
        for (int c = 0; c < 4; ++c) acc[a][c] = fmaf(wq[a], yq[c], acc[a][c]);
    }

    // epilogue: relu(acc + b1), write HT[o][g0+n] (float4 over n)
#pragma unroll
    for (int a = 0; a < 4; ++a) {
      const float bb = b1s[o0 + a];
      float4 v;
      v.x = fmaxf(acc[a][0] + bb, 0.0f);
      v.y = fmaxf(acc[a][1] + bb, 0.0f);
      v.z = fmaxf(acc[a][2] + bb, 0.0f);
      v.w = fmaxf(acc[a][3] + bb, 0.0f);
      *(float4*)&HT[(size_t)(o0 + a) * 65536 + g0 + n0] = v;
    }
  }
}

// ---------------------------------------------------------------------------
// Kernel C: fc2 (128->256). 2 output families of 128; w2 half transposed in
// LDS once per block. Grid: 512 blocks x 512 threads, 4 chunks of 64 groups.
__global__ __launch_bounds__(512) void fc2_kernel(
    const float* __restrict__ HT,
    const float* __restrict__ w2, const float* __restrict__ b2,
    float* __restrict__ out) {
  __shared__ float w2T[128][132];  // 67,584 B
  __shared__ float Hs[128][68];    // 34,816 B

  const int tid = threadIdx.x;
  const int fam = blockIdx.x & 1;
  const int nb  = blockIdx.x >> 1;  // 0..255

  // one-time: transpose w2 half into LDS (coalesced global read)
  const float* w2f = w2 + (size_t)fam * 128 * 128;
  for (int i = tid; i < 128 * 128; i += 512) {
    int o = i >> 7, k = i & 127;
    w2T[k][o] = w2f[i];
  }

  const int to = tid & 31, tn = tid >> 5;
  const int o0 = 4 * to, n0 = 4 * tn;
  const float4 b2v = *(const float4*)&b2[fam * 128 + o0];

  for (int it = 0; it < 4; ++it) {
    const int ch = nb * 4 + it;          // 0..1023
    const size_t g0 = (size_t)ch * 64;

    __syncthreads();  // protect Hs reuse (and w2T on first pass)

    // stage HT chunk: Hs[k][n] <- HT[k][g0+n]
    for (int i = tid; i < 128 * 64; i += 512) {
      const int k = i >> 6, n = i & 63;
      Hs[k][n] = HT[(size_t)k * 65536 + g0 + n];
    }
    __syncthreads();

    float acc[4][4];
#pragma unroll
    for (int a = 0; a < 4; ++a)
#pragma unroll
      for (int c = 0; c < 4; ++c) acc[a][c] = 0.0f;

#pragma unroll 2
    for (int k = 0; k < 128; ++k) {
      const float4 wv = *(const float4*)&w2T[k][o0];
      const float4 hv = *(const float4*)&Hs[k][n0];
      const float wq[4] = {wv.x, wv.y, wv.z, wv.w};
      const float hq[4] = {hv.x, hv.y, hv.z, hv.w};
#pragma unroll
      for (int a = 0; a < 4; ++a)
#pragma unroll
        for (int c = 0; c < 4; ++c) acc[a][c] = fmaf(wq[a], hq[c], acc[a][c]);
    }

    // epilogue: out[(g0+n)*256 + fam*128 + o0 .. +3] (float4 over o)
#pragma unroll
    for (int c = 0; c < 4; ++c) {
      float4 v;
      v.x = acc[0][c] + b2v.x;
      v.y = acc[1][c] + b2v.y;
      v.z = acc[2][c] + b2v.z;
      v.w = acc[3][c] + b2v.w;
      *(float4*)&out[(g0 + n0 + c) * 256 + fam * 128 + o0] = v;
    }
  }
}

// ---------------------------------------------------------------------------
// Fallback fused MLP (known-good) if ws is too small for HT.
#define GPB 16
__global__ __launch_bounds__(256) void mlp_kernel(
    const float* __restrict__ A,
    const float* __restrict__ cw, const float* __restrict__ cb,
    const float* __restrict__ w1, const float* __restrict__ b1,
    const float* __restrict__ w2, const float* __restrict__ b2,
    float* __restrict__ out) {
  __shared__ float s_io[GPB * 256];
  __shared__ float s_y[GPB][92];
  __shared__ float s_h[GPB][132];

  const int tid = threadIdx.x;
  const size_t nb = blockIdx.x;

  const float* src = A + nb * (GPB * 180);
  for (int i = tid; i < GPB * 180; i += 256) s_io[i] = src[i];
  __syncthreads();

  float cwr[2][7];
#pragma unroll
  for (int r = 0; r < 2; ++r)
#pragma unroll
    for (int k = 0; k < 7; ++k) cwr[r][k] = cw[r * 7 + k];
  const float cbv = cb[0];

  for (int o = tid; o < GPB * 90; o += 256) {
    const int g = o / 90, j = o % 90;
    float acc = cbv;
#pragma unroll
    for (int r = 0; r < 2; ++r)
#pragma unroll
      for (int k = 0; k < 7; ++k) {
        const int m = j + k - 3;
        if (m >= 0 && m < 90) acc = fmaf(s_io[g * 180 + r * 90 + m], cwr[r][k], acc);
      }
    s_y[g][j] = fmaxf(acc, 0.0f);
  }
  __syncthreads();

  const int g = tid & 15, olo = tid >> 4;
  {
    float acc[8];
#pragma unroll
    for (int i = 0; i < 8; ++i) acc[i] = b1[olo + 16 * i];
    const float2* w1v = (const float2*)w1;
    for (int k2 = 0; k2 < 45; ++k2) {
      const float2 yv = *(const float2*)&s_y[g][2 * k2];
#pragma unroll
      for (int i = 0; i < 8; ++i) {
        const float2 wv = w1v[(size_t)(olo + 16 * i) * 45 + k2];
        acc[i] = fmaf(yv.x, wv.x, acc[i]);
        acc[i] = fmaf(yv.y, wv.y, acc[i]);
      }
    }
#pragma unroll
    for (int i = 0; i < 8; ++i) s_h[g][olo + 16 * i] = fmaxf(acc[i], 0.0f);
  }
  __syncthreads();
  {
    float acc[16];
#pragma unroll
    for (int i = 0; i < 16; ++i) acc[i] = b2[olo + 16 * i];
    const float4* w2v = (const float4*)w2;
    for (int k4 = 0; k4 < 32; ++k4) {
      const float4 hv = *(const float4*)&s_h[g][4 * k4];
#pragma unroll
      for (int i = 0; i < 16; ++i) {
        const float4 wv = w2v[(size_t)(olo + 16 * i) * 32 + k4];
        acc[i] = fmaf(hv.x, wv.x, acc[i]);
        acc[i] = fmaf(hv.y, wv.y, acc[i]);
        acc[i] = fmaf(hv.z, wv.z, acc[i]);
        acc[i] = fmaf(hv.w, wv.w, acc[i]);
      }
    }
#pragma unroll
    for (int i = 0; i < 16; ++i) s_io[g * 256 + olo + 16 * i] = acc[i];
  }
  __syncthreads();
  float* dst = out + nb * (GPB * 256);
  for (int i = tid; i < GPB * 256; i += 256) dst[i] = s_io[i];
}

extern "C" void kernel_launch(void* const* d_in, const int* in_sizes, int n_in,
                              void* d_out, int out_size, void* d_ws, size_t ws_size,
                              hipStream_t stream) {
  const float* x  = (const float*)d_in[0];
  const float* cw = (const float*)d_in[1];
  const float* cb = (const float*)d_in[2];
  const float* w1 = (const float*)d_in[3];
  const float* b1 = (const float*)d_in[4];
  const float* w2 = (const float*)d_in[5];
  const float* b2 = (const float*)d_in[6];
  float* outp = (float*)d_out;

  float* A = (float*)d_ws;                       // 11,796,480 floats (47.2 MB)
  const size_t A_elems = (size_t)16 * 180 * 4096;
  float* HT = A + A_elems;                       // 8,388,608 floats (33.6 MB)
  const size_t need = (A_elems + (size_t)128 * 65536) * sizeof(float);

  dwt2_kernel<<<1024, 256, 0, stream>>>(x, A);
  if (ws_size >= need) {
    conv_fc1_kernel<<<256, 512, 0, stream>>>(A, cw, cb, w1, b1, HT);
    fc2_kernel<<<512, 512, 0, stream>>>(HT, w2, b2, outp);
  } else {
    mlp_kernel<<<4096, 256, 0, stream>>>(A, cw, cb, w1, b1, w2, b2, outp);
  }
}

// Round 3
// 215.184 us; speedup vs baseline: 2.4515x; 1.5062x over previous
//
#include <hip/hip_runtime.h>

using bf8   = __attribute__((ext_vector_type(8))) short;
using f32x4 = __attribute__((ext_vector_type(4))) float;

__device__ inline unsigned short f2bf(float f) {
  unsigned u = __float_as_uint(f);
  return (unsigned short)((u + 0x7FFFu + ((u >> 16) & 1u)) >> 16);  // RNE
}
__device__ inline float bf2f(unsigned short h) {
  return __uint_as_float(((unsigned)h) << 16);
}

// Composite filters: 2nd-level db2 DWT on the hi branch of the 1st level
// collapses to one 10-tap stride-4 conv along channels.
struct Gs { float g0[10]; float g1[10]; };
__host__ __device__ constexpr Gs make_g() {
  double H0[4] = {0.48296291314469025, 0.836516303737469,
                  0.22414386804185735, -0.12940952255092145};
  double H1[4] = {0.12940952255092145, -0.22414386804185735,
                  0.836516303737469, -0.48296291314469025};
  Gs r{};
  for (int d = 0; d < 10; ++d) {
    double a = 0.0, b = 0.0;
    for (int k = 0; k < 4; ++k) {
      int j = d - 2 * k;
      if (j >= 0 && j < 4) { a += H0[k] * H1[j]; b += H1[k] * H1[j]; }
    }
    r.g0[d] = (float)a; r.g1[d] = (float)b;
  }
  return r;
}

// ---------------------------------------------------------------------------
// K1: x fp32 [16][360][4096] -> A bf16 (flat [16][180][4096]).
// Grid 512 = 4 seg x 16 b x 8 s-chunks; float2 pixels per thread.
__global__ __launch_bounds__(256) void dwt2_kernel(const float* __restrict__ x,
                                                   unsigned short* __restrict__ A) {
  constexpr Gs G = make_g();
  const int bx    = blockIdx.x;
  const int seg   = bx & 3;
  const int pb    = bx >> 2;      // 0..127
  const int b     = pb >> 3;      // 0..15
  const int chunk = pb & 7;       // 0..7
  const int s     = chunk * 512 + 2 * threadIdx.x;

  const float2* xb = (const float2*)(x + (size_t)b * 360 * 4096 + s);
  unsigned short* Ab = A + (size_t)b * 180 * 4096 + s;

  const int c0 = (seg * 90) >> 2;        // 0,22,45,67
  const int c1 = ((seg + 1) * 90) >> 2;  // 22,45,67,90

  float2 w[10];
  const int base = 4 * c0 - 6;
#pragma unroll
  for (int i = 0; i < 10; ++i) {
    int idx = base + i;
    w[i] = (idx >= 0) ? xb[(size_t)idx * 2048] : float2{0.f, 0.f};
  }

  for (int c = c0; c < c1; ++c) {
    float2 nx[4];
    const bool pf = (c + 1 < c1);
    const int nb = 4 * c + 4;  // <= 359
#pragma unroll
    for (int i = 0; i < 4; ++i)
      nx[i] = pf ? xb[(size_t)(nb + i) * 2048] : float2{0.f, 0.f};

    float2 lo{0.f, 0.f}, hi{0.f, 0.f};
#pragma unroll
    for (int d = 0; d < 10; ++d) {
      lo.x = fmaf(G.g0[d], w[d].x, lo.x);
      lo.y = fmaf(G.g0[d], w[d].y, lo.y);
      hi.x = fmaf(G.g1[d], w[d].x, hi.x);
      hi.y = fmaf(G.g1[d], w[d].y, hi.y);
    }
    *(ushort2*)&Ab[(size_t)c * 4096]        = ushort2{f2bf(lo.x), f2bf(lo.y)};
    *(ushort2*)&Ab[(size_t)(c + 90) * 4096] = ushort2{f2bf(hi.x), f2bf(hi.y)};
#pragma unroll
    for (int i = 0; i < 6; ++i) w[i] = w[i + 4];
#pragma unroll
    for (int i = 0; i < 4; ++i) w[6 + i] = nx[i];
  }
}

// ---------------------------------------------------------------------------
// K2: conv(2x7,pad3)+relu per flat-180 group. A bf16 -> Y bf16 [65536][96]
// (cols 90..95 zero so fc1 can run K=96 cleanly). 64 groups / 256-thr block.
__global__ __launch_bounds__(256) void conv_kernel(
    const unsigned short* __restrict__ A,
    const float* __restrict__ cw, const float* __restrict__ cb,
    unsigned short* __restrict__ Y) {
  __shared__ float As[64 * 180];  // 46,080 B -> 3 blocks/CU
  const int tid = threadIdx.x;
  const size_t g0 = (size_t)blockIdx.x * 64;

  // stage: 64*180 bf16 contiguous = 1440 uint4
  const uint4* src = (const uint4*)(A + g0 * 180);
  for (int i = tid; i < 1440; i += 256) {
    uint4 v = src[i];
    float* d = &As[8 * i];
    d[0] = bf2f((unsigned short)(v.x & 0xFFFF));
    d[1] = bf2f((unsigned short)(v.x >> 16));
    d[2] = bf2f((unsigned short)(v.y & 0xFFFF));
    d[3] = bf2f((unsigned short)(v.y >> 16));
    d[4] = bf2f((unsigned short)(v.z & 0xFFFF));
    d[5] = bf2f((unsigned short)(v.z >> 16));
    d[6] = bf2f((unsigned short)(v.w & 0xFFFF));
    d[7] = bf2f((unsigned short)(v.w >> 16));
  }
  __syncthreads();

  float cwr[14];
#pragma unroll
  for (int k = 0; k < 14; ++k) cwr[k] = cw[k];
  const float cbv = cb[0];

  // 24 j-quads per group (covers 96 padded cols); window read 10+10 values
  for (int i = tid; i < 64 * 24; i += 256) {
    const int g = i / 24, j4 = i - g * 24, j0 = 4 * j4;
    const float* Ag = &As[g * 180];
    float v0[10], v1[10];
#pragma unroll
    for (int t = 0; t < 10; ++t) {
      const int m = j0 - 3 + t;
      const bool ok = (m >= 0) && (m < 90);
      v0[t] = ok ? Ag[m] : 0.0f;
      v1[t] = ok ? Ag[90 + m] : 0.0f;
    }
    ushort4 o4;
    unsigned short* op = (unsigned short*)&o4;
#pragma unroll
    for (int d = 0; d < 4; ++d) {
      const int j = j0 + d;
      float acc = 0.0f;
      if (j < 90) {
        acc = cbv;
#pragma unroll
        for (int k = 0; k < 7; ++k) {
          acc = fmaf(v0[d + k], cwr[k], acc);
          acc = fmaf(v1[d + k], cwr[7 + k], acc);
        }
        acc = fmaxf(acc, 0.0f);
      }
      op[d] = f2bf(acc);
    }
    *(ushort4*)&Y[(g0 + g) * 96 + j0] = o4;
  }
}

// ---------------------------------------------------------------------------
// K3: fused fc1 (96->128, relu) + fc2 (128->256) with bf16 MFMA 16x16x32.
// Layouts (guide-verified): A/B frag: row = lane&15, k = (lane>>4)*8 + j;
// C/D: col = lane&15, row = (lane>>4)*4 + reg.
// 512 threads (8 waves), 128 groups/block, grid 512. LDS 132.6 KB.
__global__ __launch_bounds__(512) void mlp_mfma_kernel(
    const unsigned short* __restrict__ Y,
    const float* __restrict__ w1, const float* __restrict__ b1,
    const float* __restrict__ w2, const float* __restrict__ b2,
    float* __restrict__ out) {
  __shared__ unsigned short w1B[128 * 104];  // [o1][k<=96], stride 104 (2-way banks, 16B rows)
  __shared__ unsigned short w2B[256 * 136];  // [o2][k=128], stride 136
  __shared__ unsigned short HY[128 * 136];   // Yb (stride 104) then Hb (stride 136), aliased
  __shared__ float b1s[128];
  __shared__ float b2s[256];

  const int tid = threadIdx.x;
  const size_t g0 = (size_t)blockIdx.x * 128;

  // ---- stage weights (bf16) + Y chunk ----
  for (int i = tid; i < 128 * 90; i += 512) {
    const int o = i / 90, k = i - o * 90;
    w1B[o * 104 + k] = f2bf(w1[i]);
  }
  for (int i = tid; i < 128 * 6; i += 512) {
    const int o = i / 6, k = 90 + (i - o * 6);
    w1B[o * 104 + k] = 0;  // zero-pad K 90..95
  }
  const float4* w2v = (const float4*)w2;
  for (int i = tid; i < 8192; i += 512) {  // 256 rows x 32 float4
    const int o = i >> 5, k4 = i & 31;
    const float4 v = w2v[i];
    *(ushort4*)&w2B[o * 136 + 4 * k4] =
        ushort4{f2bf(v.x), f2bf(v.y), f2bf(v.z), f2bf(v.w)};
  }
  const uint4* ys = (const uint4*)(Y + g0 * 96);
  for (int i = tid; i < 1536; i += 512) {  // 128 rows x 12 uint4
    const int r = i / 12, c8 = i - r * 12;
    *(uint4*)&HY[r * 104 + 8 * c8] = ys[i];
  }
  if (tid < 128) b1s[tid] = b1[tid];
  if (tid < 256) b2s[tid] = b2[tid];
  __syncthreads();

  const int w = tid >> 6, lane = tid & 63;
  const int l15 = lane & 15, q = lane >> 4;
  const int mrow = 16 * w + l15;  // group row this lane supplies to A-frags

  // ---- fc1: D[n-group][o1], K=96 ----
  bf8 ya[3];
#pragma unroll
  for (int ks = 0; ks < 3; ++ks)
    ya[ks] = *(const bf8*)&HY[mrow * 104 + 32 * ks + 8 * q];

  f32x4 acc1[8];
#pragma unroll
  for (int nt = 0; nt < 8; ++nt) {
    f32x4 a = {0.f, 0.f, 0.f, 0.f};
#pragma unroll
    for (int ks = 0; ks < 3; ++ks) {
      const bf8 wb = *(const bf8*)&w1B[(16 * nt + l15) * 104 + 32 * ks + 8 * q];
      a = __builtin_amdgcn_mfma_f32_16x16x32_bf16(ya[ks], wb, a, 0, 0, 0);
    }
    acc1[nt] = a;
  }
  __syncthreads();  // all waves finished reading Yb before Hb overwrites it

  // epilogue: +b1, relu, bf16 -> Hb[n][o1] (stride 136)
#pragma unroll
  for (int nt = 0; nt < 8; ++nt) {
#pragma unroll
    for (int r = 0; r < 4; ++r) {
      const int n = 16 * w + 4 * q + r;
      const int o = 16 * nt + l15;
      float v = acc1[nt][r] + b1s[o];
      v = fmaxf(v, 0.0f);
      HY[n * 136 + o] = f2bf(v);
    }
  }
  __syncthreads();

  // ---- fc2: D[n-group][o2], K=128 ----
  bf8 ha[4];
#pragma unroll
  for (int ks = 0; ks < 4; ++ks)
    ha[ks] = *(const bf8*)&HY[mrow * 136 + 32 * ks + 8 * q];

#pragma unroll 4
  for (int nt = 0; nt < 16; ++nt) {
    f32x4 a = {0.f, 0.f, 0.f, 0.f};
#pragma unroll
    for (int ks = 0; ks < 4; ++ks) {
      const bf8 wb = *(const bf8*)&w2B[(16 * nt + l15) * 136 + 32 * ks + 8 * q];
      a = __builtin_amdgcn_mfma_f32_16x16x32_bf16(ha[ks], wb, a, 0, 0, 0);
    }
#pragma unroll
    for (int r = 0; r < 4; ++r) {
      const int n = 16 * w + 4 * q + r;
      const int o = 16 * nt + l15;
      out[(g0 + n) * 256 + o] = a[r] + b2s[o];
    }
  }
}

// ---------------------------------------------------------------------------
extern "C" void kernel_launch(void* const* d_in, const int* in_sizes, int n_in,
                              void* d_out, int out_size, void* d_ws, size_t ws_size,
                              hipStream_t stream) {
  const float* x  = (const float*)d_in[0];
  const float* cw = (const float*)d_in[1];
  const float* cb = (const float*)d_in[2];
  const float* w1 = (const float*)d_in[3];
  const float* b1 = (const float*)d_in[4];
  const float* w2 = (const float*)d_in[5];
  const float* b2 = (const float*)d_in[6];
  float* outp = (float*)d_out;

  unsigned short* Abf = (unsigned short*)d_ws;          // 16*180*4096 bf16 = 23.6 MB
  unsigned short* Ybf = Abf + (size_t)16 * 180 * 4096;  // 65536*96 bf16 = 12.6 MB

  dwt2_kernel<<<512, 256, 0, stream>>>(x, Abf);
  conv_kernel<<<1024, 256, 0, stream>>>(Abf, cw, cb, Ybf);
  mlp_mfma_kernel<<<512, 512, 0, stream>>>(Ybf, w1, b1, w2, b2, outp);
}

// Round 4
// 213.459 us; speedup vs baseline: 2.4713x; 1.0081x over previous
//
#include <hip/hip_runtime.h>

using bf8   = __attribute__((ext_vector_type(8))) short;
using f32x4 = __attribute__((ext_vector_type(4))) float;

__device__ inline unsigned short f2bf(float f) {
  unsigned u = __float_as_uint(f);
  return (unsigned short)((u + 0x7FFFu + ((u >> 16) & 1u)) >> 16);  // RNE
}
__device__ inline float bf2f(unsigned short h) {
  return __uint_as_float(((unsigned)h) << 16);
}

// Composite filters: 2nd-level db2 DWT on the hi branch of the 1st level
// collapses to one 10-tap stride-4 conv along channels.
struct Gs { float g0[10]; float g1[10]; };
__host__ __device__ constexpr Gs make_g() {
  double H0[4] = {0.48296291314469025, 0.836516303737469,
                  0.22414386804185735, -0.12940952255092145};
  double H1[4] = {0.12940952255092145, -0.22414386804185735,
                  0.836516303737469, -0.48296291314469025};
  Gs r{};
  for (int d = 0; d < 10; ++d) {
    double a = 0.0, b = 0.0;
    for (int k = 0; k < 4; ++k) {
      int j = d - 2 * k;
      if (j >= 0 && j < 4) { a += H0[k] * H1[j]; b += H1[k] * H1[j]; }
    }
    r.g0[d] = (float)a; r.g1[d] = (float)b;
  }
  return r;
}

// ---------------------------------------------------------------------------
// K1: x fp32 [16][360][4096] -> A bf16 (flat [16][180][4096]); float4/thread.
// Blocks 0..511: 8 seg x 16 b x 4 s-chunks. Blocks 512..558: weight prep
// (w1 -> bf16 [128][104] zero-padded K, w2 -> bf16 [256][136]).
__global__ __launch_bounds__(256) void dwt2_kernel(
    const float* __restrict__ x, unsigned short* __restrict__ A,
    const float* __restrict__ w1, const float* __restrict__ w2,
    unsigned short* __restrict__ w1b, unsigned short* __restrict__ w2b) {
  const int bx = blockIdx.x;
  if (bx >= 512) {  // ---- weight prep: 47 blocks x 1024 elems = 48128 ----
    const int e = bx - 512;
#pragma unroll
    for (int t = 0; t < 4; ++t) {
      const int i = e * 1024 + t * 256 + threadIdx.x;
      if (i < 13312) {                       // w1b: 128 x 104
        const int o = i / 104, k = i - 104 * o;
        w1b[i] = (k < 90) ? f2bf(w1[o * 90 + k]) : (unsigned short)0;
      } else {                               // w2b: 256 x 136
        const int j = i - 13312;
        const int o = j / 136, k = j - 136 * o;
        w2b[j] = (k < 128) ? f2bf(w2[o * 128 + k]) : (unsigned short)0;
      }
    }
    return;
  }

  constexpr Gs G = make_g();
  const int seg   = bx & 7;
  const int pb    = bx >> 3;      // 0..63
  const int b     = pb >> 2;      // 0..15
  const int chunk = pb & 3;       // 0..3
  const int s     = chunk * 1024 + 4 * threadIdx.x;

  const float4* xb = (const float4*)(x + (size_t)b * 360 * 4096 + s);
  unsigned short* Ab = A + (size_t)b * 180 * 4096 + s;
  // channel stride: 1024 float4

  const int c0 = (seg * 90) >> 3;
  const int c1 = ((seg + 1) * 90) >> 3;

  float4 w[10];
  const int base = 4 * c0 - 6;
#pragma unroll
  for (int i = 0; i < 10; ++i) {
    const int idx = base + i;
    w[i] = (idx >= 0) ? xb[(size_t)idx * 1024] : float4{0.f, 0.f, 0.f, 0.f};
  }

  for (int c = c0; c < c1; ++c) {
    float4 nx[4];
    const bool pf = (c + 1 < c1);
    const int nb = 4 * c + 4;  // <= 359
#pragma unroll
    for (int i = 0; i < 4; ++i)
      nx[i] = pf ? xb[(size_t)(nb + i) * 1024] : float4{0.f, 0.f, 0.f, 0.f};

    float4 lo{0.f, 0.f, 0.f, 0.f}, hi{0.f, 0.f, 0.f, 0.f};
#pragma unroll
    for (int d = 0; d < 10; ++d) {
      lo.x = fmaf(G.g0[d], w[d].x, lo.x);
      lo.y = fmaf(G.g0[d], w[d].y, lo.y);
      lo.z = fmaf(G.g0[d], w[d].z, lo.z);
      lo.w = fmaf(G.g0[d], w[d].w, lo.w);
      hi.x = fmaf(G.g1[d], w[d].x, hi.x);
      hi.y = fmaf(G.g1[d], w[d].y, hi.y);
      hi.z = fmaf(G.g1[d], w[d].z, hi.z);
      hi.w = fmaf(G.g1[d], w[d].w, hi.w);
    }
    *(ushort4*)&Ab[(size_t)c * 4096] =
        ushort4{f2bf(lo.x), f2bf(lo.y), f2bf(lo.z), f2bf(lo.w)};
    *(ushort4*)&Ab[(size_t)(c + 90) * 4096] =
        ushort4{f2bf(hi.x), f2bf(hi.y), f2bf(hi.z), f2bf(hi.w)};
#pragma unroll
    for (int i = 0; i < 6; ++i) w[i] = w[i + 4];
#pragma unroll
    for (int i = 0; i < 4; ++i) w[6 + i] = nx[i];
  }
}

// ---------------------------------------------------------------------------
// K2: conv(2x7,pad3)+relu per flat-180 group. A bf16 -> Y bf16 [65536][96]
// (cols 90..95 zero). 64 groups / 256-thr block.
__global__ __launch_bounds__(256) void conv_kernel(
    const unsigned short* __restrict__ A,
    const float* __restrict__ cw, const float* __restrict__ cb,
    unsigned short* __restrict__ Y) {
  __shared__ float As[64 * 180];  // 46,080 B -> 3 blocks/CU
  const int tid = threadIdx.x;
  const size_t g0 = (size_t)blockIdx.x * 64;

  const uint4* src = (const uint4*)(A + g0 * 180);
  for (int i = tid; i < 1440; i += 256) {
    uint4 v = src[i];
    float* d = &As[8 * i];
    d[0] = bf2f((unsigned short)(v.x & 0xFFFF));
    d[1] = bf2f((unsigned short)(v.x >> 16));
    d[2] = bf2f((unsigned short)(v.y & 0xFFFF));
    d[3] = bf2f((unsigned short)(v.y >> 16));
    d[4] = bf2f((unsigned short)(v.z & 0xFFFF));
    d[5] = bf2f((unsigned short)(v.z >> 16));
    d[6] = bf2f((unsigned short)(v.w & 0xFFFF));
    d[7] = bf2f((unsigned short)(v.w >> 16));
  }
  __syncthreads();

  float cwr[14];
#pragma unroll
  for (int k = 0; k < 14; ++k) cwr[k] = cw[k];
  const float cbv = cb[0];

  for (int i = tid; i < 64 * 24; i += 256) {
    const int g = i / 24, j4 = i - g * 24, j0 = 4 * j4;
    const float* Ag = &As[g * 180];
    float v0[10], v1[10];
#pragma unroll
    for (int t = 0; t < 10; ++t) {
      const int m = j0 - 3 + t;
      const bool ok = (m >= 0) && (m < 90);
      v0[t] = ok ? Ag[m] : 0.0f;
      v1[t] = ok ? Ag[90 + m] : 0.0f;
    }
    ushort4 o4;
    unsigned short* op = (unsigned short*)&o4;
#pragma unroll
    for (int d = 0; d < 4; ++d) {
      const int j = j0 + d;
      float acc = 0.0f;
      if (j < 90) {
        acc = cbv;
#pragma unroll
        for (int k = 0; k < 7; ++k) {
          acc = fmaf(v0[d + k], cwr[k], acc);
          acc = fmaf(v1[d + k], cwr[7 + k], acc);
        }
        acc = fmaxf(acc, 0.0f);
      }
      op[d] = f2bf(acc);
    }
    *(ushort4*)&Y[(g0 + g) * 96 + j0] = o4;
  }
}

// ---------------------------------------------------------------------------
// K3: fused fc1 (96->128, relu) + fc2 half (128->128) with bf16 MFMA 16x16x32.
// Output-family split: fam = blockIdx&1 selects w2 rows [fam*128, fam*128+128).
// 64 groups/block, 256 thr (4 waves), LDS 79,872 B -> 2 blocks/CU.
// Frag layouts (validated round 3): A/B row = lane&15, k = (lane>>4)*8 + j;
// C/D col(B-row) = lane&15, row(A-row) = (lane>>4)*4 + reg.
__global__ __launch_bounds__(256) void mlp_mfma_kernel(
    const unsigned short* __restrict__ Y,
    const unsigned short* __restrict__ w1b,
    const unsigned short* __restrict__ w2b,
    const float* __restrict__ b1, const float* __restrict__ b2,
    float* __restrict__ out) {
  __shared__ unsigned short w1B[128 * 104];  // 26,624 B [o1][k<=96]
  __shared__ unsigned short w2B[128 * 136];  // 34,816 B [o2-half][k=128]
  __shared__ unsigned short HY[64 * 136];    // 17,408 B: Yb (stride 104) then Hb (stride 136)
  __shared__ float bias[256];                // b1 | b2-half

  const int tid = threadIdx.x;
  const int fam = blockIdx.x & 1;
  const size_t g0 = (size_t)(blockIdx.x >> 1) * 64;

  // ---- stage (pure uint4 copies; weights pre-converted in K1) ----
  {
    const uint4* s1 = (const uint4*)w1b;                              // 1664
    for (int i = tid; i < 1664; i += 256) ((uint4*)w1B)[i] = s1[i];
    const uint4* s2 = (const uint4*)(w2b + (size_t)fam * 128 * 136);  // 2176
    for (int i = tid; i < 2176; i += 256) ((uint4*)w2B)[i] = s2[i];
    const uint4* ys = (const uint4*)(Y + g0 * 96);                    // 768
    for (int i = tid; i < 768; i += 256) {
      const int r = i / 12, c = i - 12 * r;
      *(uint4*)&HY[r * 104 + 8 * c] = ys[i];
    }
    bias[tid] = (tid < 128) ? b1[tid] : b2[fam * 128 + (tid - 128)];
  }
  __syncthreads();

  const int w = tid >> 6, lane = tid & 63;
  const int l15 = lane & 15, q = lane >> 4;
  const int mrow = 16 * w + l15;  // group row this lane supplies to A-frags

  // ---- fc1: K=96 ----
  bf8 ya[3];
#pragma unroll
  for (int ks = 0; ks < 3; ++ks)
    ya[ks] = *(const bf8*)&HY[mrow * 104 + 32 * ks + 8 * q];

  f32x4 acc1[8];
#pragma unroll
  for (int nt = 0; nt < 8; ++nt) {
    f32x4 a = {0.f, 0.f, 0.f, 0.f};
#pragma unroll
    for (int ks = 0; ks < 3; ++ks) {
      const bf8 wb = *(const bf8*)&w1B[(16 * nt + l15) * 104 + 32 * ks + 8 * q];
      a = __builtin_amdgcn_mfma_f32_16x16x32_bf16(ya[ks], wb, a, 0, 0, 0);
    }
    acc1[nt] = a;
  }
  __syncthreads();  // Yb fully consumed before Hb overwrites the union

  // epilogue 1: +b1, relu -> Hb[n][o1] bf16 (stride 136)
#pragma unroll
  for (int nt = 0; nt < 8; ++nt) {
#pragma unroll
    for (int r = 0; r < 4; ++r) {
      const int n = 16 * w + 4 * q + r;
      const int o = 16 * nt + l15;
      HY[n * 136 + o] = f2bf(fmaxf(acc1[nt][r] + bias[o], 0.0f));
    }
  }
  __syncthreads();

  // ---- fc2 half: K=128, 8 output tiles ----
  bf8 ha[4];
#pragma unroll
  for (int ks = 0; ks < 4; ++ks)
    ha[ks] = *(const bf8*)&HY[mrow * 136 + 32 * ks + 8 * q];

#pragma unroll 2
  for (int nt = 0; nt < 8; ++nt) {
    f32x4 a = {0.f, 0.f, 0.f, 0.f};
#pragma unroll
    for (int ks = 0; ks < 4; ++ks) {
      const bf8 wb = *(const bf8*)&w2B[(16 * nt + l15) * 136 + 32 * ks + 8 * q];
      a = __builtin_amdgcn_mfma_f32_16x16x32_bf16(ha[ks], wb, a, 0, 0, 0);
    }
#pragma unroll
    for (int r = 0; r < 4; ++r) {
      const int n = 16 * w + 4 * q + r;
      const int o = 16 * nt + l15;
      out[(g0 + n) * 256 + fam * 128 + o] = a[r] + bias[128 + o];
    }
  }
}

// ---------------------------------------------------------------------------
extern "C" void kernel_launch(void* const* d_in, const int* in_sizes, int n_in,
                              void* d_out, int out_size, void* d_ws, size_t ws_size,
                              hipStream_t stream) {
  const float* x  = (const float*)d_in[0];
  const float* cw = (const float*)d_in[1];
  const float* cb = (const float*)d_in[2];
  const float* w1 = (const float*)d_in[3];
  const float* b1 = (const float*)d_in[4];
  const float* w2 = (const float*)d_in[5];
  const float* b2 = (const float*)d_in[6];
  float* outp = (float*)d_out;

  unsigned short* Abf = (unsigned short*)d_ws;          // 16*180*4096 = 23.6 MB
  unsigned short* Ybf = Abf + (size_t)16 * 180 * 4096;  // 65536*96    = 12.6 MB
  unsigned short* w1b = Ybf + (size_t)65536 * 96;       // 128*104
  unsigned short* w2b = w1b + 13312;                    // 256*136

  dwt2_kernel<<<559, 256, 0, stream>>>(x, Abf, w1, w2, w1b, w2b);
  conv_kernel<<<1024, 256, 0, stream>>>(Abf, cw, cb, Ybf);
  mlp_mfma_kernel<<<2048, 256, 0, stream>>>(Ybf, w1b, w2b, b1, b2, outp);
}

// Round 5
// 206.780 us; speedup vs baseline: 2.5511x; 1.0323x over previous
//
#include <hip/hip_runtime.h>

using bf8   = __attribute__((ext_vector_type(8))) short;
using f32x4 = __attribute__((ext_vector_type(4))) float;

__device__ inline unsigned short f2bf(float f) {
  unsigned u = __float_as_uint(f);
  return (unsigned short)((u + 0x7FFFu + ((u >> 16) & 1u)) >> 16);  // RNE
}
__device__ inline float bf2f(unsigned short h) {
  return __uint_as_float(((unsigned)h) << 16);
}

// Composite filters: 2nd-level db2 DWT on the hi branch of the 1st level
// collapses to one 10-tap stride-4 conv along channels.
struct Gs { float g0[10]; float g1[10]; };
__host__ __device__ constexpr Gs make_g() {
  double H0[4] = {0.48296291314469025, 0.836516303737469,
                  0.22414386804185735, -0.12940952255092145};
  double H1[4] = {0.12940952255092145, -0.22414386804185735,
                  0.836516303737469, -0.48296291314469025};
  Gs r{};
  for (int d = 0; d < 10; ++d) {
    double a = 0.0, b = 0.0;
    for (int k = 0; k < 4; ++k) {
      int j = d - 2 * k;
      if (j >= 0 && j < 4) { a += H0[k] * H1[j]; b += H1[k] * H1[j]; }
    }
    r.g0[d] = (float)a; r.g1[d] = (float)b;
  }
  return r;
}

// ---------------------------------------------------------------------------
// K1: x fp32 [16][360][4096] -> A bf16 (flat [16][180][4096]); float4/thread.
// Grid 512 = 8 seg x 16 b x 4 s-chunks (exactly 2 blocks/CU).
__global__ __launch_bounds__(256) void dwt2_kernel(const float* __restrict__ x,
                                                   unsigned short* __restrict__ A) {
  constexpr Gs G = make_g();
  const int bx    = blockIdx.x;
  const int seg   = bx & 7;
  const int pb    = bx >> 3;      // 0..63
  const int b     = pb >> 2;      // 0..15
  const int chunk = pb & 3;       // 0..3
  const int s     = chunk * 1024 + 4 * threadIdx.x;

  const float4* xb = (const float4*)(x + (size_t)b * 360 * 4096 + s);
  unsigned short* Ab = A + (size_t)b * 180 * 4096 + s;
  // channel stride: 1024 float4

  const int c0 = (seg * 90) >> 3;
  const int c1 = ((seg + 1) * 90) >> 3;

  float4 w[10];
  const int base = 4 * c0 - 6;
#pragma unroll
  for (int i = 0; i < 10; ++i) {
    const int idx = base + i;
    w[i] = (idx >= 0) ? xb[(size_t)idx * 1024] : float4{0.f, 0.f, 0.f, 0.f};
  }

  for (int c = c0; c < c1; ++c) {
    float4 nx[4];
    const bool pf = (c + 1 < c1);
    const int nb = 4 * c + 4;  // <= 359
#pragma unroll
    for (int i = 0; i < 4; ++i)
      nx[i] = pf ? xb[(size_t)(nb + i) * 1024] : float4{0.f, 0.f, 0.f, 0.f};

    float4 lo{0.f, 0.f, 0.f, 0.f}, hi{0.f, 0.f, 0.f, 0.f};
#pragma unroll
    for (int d = 0; d < 10; ++d) {
      lo.x = fmaf(G.g0[d], w[d].x, lo.x);
      lo.y = fmaf(G.g0[d], w[d].y, lo.y);
      lo.z = fmaf(G.g0[d], w[d].z, lo.z);
      lo.w = fmaf(G.g0[d], w[d].w, lo.w);
      hi.x = fmaf(G.g1[d], w[d].x, hi.x);
      hi.y = fmaf(G.g1[d], w[d].y, hi.y);
      hi.z = fmaf(G.g1[d], w[d].z, hi.z);
      hi.w = fmaf(G.g1[d], w[d].w, hi.w);
    }
    *(ushort4*)&Ab[(size_t)c * 4096] =
        ushort4{f2bf(lo.x), f2bf(lo.y), f2bf(lo.z), f2bf(lo.w)};
    *(ushort4*)&Ab[(size_t)(c + 90) * 4096] =
        ushort4{f2bf(hi.x), f2bf(hi.y), f2bf(hi.z), f2bf(hi.w)};
#pragma unroll
    for (int i = 0; i < 6; ++i) w[i] = w[i + 4];
#pragma unroll
    for (int i = 0; i < 4; ++i) w[6 + i] = nx[i];
  }
}

// ---------------------------------------------------------------------------
// K2: conv(2x7,pad3)+relu per flat-180 group. A bf16 -> Y bf16 [65536][96]
// (cols 90..95 zero). 64 groups / 256-thr block. Blocks >= 1024 do the
// one-time weight bf16 pre-conversion (w1 -> [128][104], w2 -> [256][136]).
__global__ __launch_bounds__(256) void conv_kernel(
    const unsigned short* __restrict__ A,
    const float* __restrict__ cw, const float* __restrict__ cb,
    unsigned short* __restrict__ Y,
    const float* __restrict__ w1, const float* __restrict__ w2,
    unsigned short* __restrict__ w1b, unsigned short* __restrict__ w2b) {
  const int bx = blockIdx.x;
  if (bx >= 1024) {  // ---- weight prep: 47 blocks x 1024 elems = 48128 ----
    const int e = bx - 1024;
#pragma unroll
    for (int t = 0; t < 4; ++t) {
      const int i = e * 1024 + t * 256 + threadIdx.x;
      if (i < 13312) {                       // w1b: 128 x 104
        const int o = i / 104, k = i - 104 * o;
        w1b[i] = (k < 90) ? f2bf(w1[o * 90 + k]) : (unsigned short)0;
      } else {                               // w2b: 256 x 136
        const int j = i - 13312;
        const int o = j / 136, k = j - 136 * o;
        w2b[j] = (k < 128) ? f2bf(w2[o * 128 + k]) : (unsigned short)0;
      }
    }
    return;
  }

  __shared__ float As[64 * 180];  // 46,080 B
  const int tid = threadIdx.x;
  const size_t g0 = (size_t)bx * 64;

  const uint4* src = (const uint4*)(A + g0 * 180);
  for (int i = tid; i < 1440; i += 256) {
    uint4 v = src[i];
    float* d = &As[8 * i];
    d[0] = bf2f((unsigned short)(v.x & 0xFFFF));
    d[1] = bf2f((unsigned short)(v.x >> 16));
    d[2] = bf2f((unsigned short)(v.y & 0xFFFF));
    d[3] = bf2f((unsigned short)(v.y >> 16));
    d[4] = bf2f((unsigned short)(v.z & 0xFFFF));
    d[5] = bf2f((unsigned short)(v.z >> 16));
    d[6] = bf2f((unsigned short)(v.w & 0xFFFF));
    d[7] = bf2f((unsigned short)(v.w >> 16));
  }
  __syncthreads();

  float cwr[14];
#pragma unroll
  for (int k = 0; k < 14; ++k) cwr[k] = cw[k];
  const float cbv = cb[0];

  for (int i = tid; i < 64 * 24; i += 256) {
    const int g = i / 24, j4 = i - g * 24, j0 = 4 * j4;
    const float* Ag = &As[g * 180];
    float v0[10], v1[10];
#pragma unroll
    for (int t = 0; t < 10; ++t) {
      const int m = j0 - 3 + t;
      const bool ok = (m >= 0) && (m < 90);
      v0[t] = ok ? Ag[m] : 0.0f;
      v1[t] = ok ? Ag[90 + m] : 0.0f;
    }
    ushort4 o4;
    unsigned short* op = (unsigned short*)&o4;
#pragma unroll
    for (int d = 0; d < 4; ++d) {
      const int j = j0 + d;
      float acc = 0.0f;
      if (j < 90) {
        acc = cbv;
#pragma unroll
        for (int k = 0; k < 7; ++k) {
          acc = fmaf(v0[d + k], cwr[k], acc);
          acc = fmaf(v1[d + k], cwr[7 + k], acc);
        }
        acc = fmaxf(acc, 0.0f);
      }
      op[d] = f2bf(acc);
    }
    *(ushort4*)&Y[(g0 + g) * 96 + j0] = o4;
  }
}

// ---------------------------------------------------------------------------
// K3: fused fc1 (96->128, relu) + fc2 half (128->128), bf16 MFMA 16x16x32.
// PERSISTENT: grid 512 (2 blocks/CU), weights staged once, 4 chunk-iterations
// of 64 groups each. fam = blockIdx&1 selects w2 rows [fam*128, +128).
// LDS 79.9 KB -> 2 blocks/CU. Frag layouts (validated): A/B row = lane&15,
// k = (lane>>4)*8 + j; C/D col(B-row) = lane&15, row(A-row) = (lane>>4)*4+reg.
__global__ __launch_bounds__(256) void mlp_mfma_kernel(
    const unsigned short* __restrict__ Y,
    const unsigned short* __restrict__ w1b,
    const unsigned short* __restrict__ w2b,
    const float* __restrict__ b1, const float* __restrict__ b2,
    float* __restrict__ out) {
  __shared__ unsigned short w1B[128 * 104];  // 26,624 B [o1][k<=96]
  __shared__ unsigned short w2B[128 * 136];  // 34,816 B [o2-half][k=128]
  __shared__ unsigned short HY[64 * 136];    // 17,408 B: Yb (104) then Hb (136)
  __shared__ float bias[256];                // b1 | b2-half

  const int tid = threadIdx.x;
  const int fam = blockIdx.x & 1;
  const int cb  = blockIdx.x >> 1;  // 0..255

  // ---- stage weights ONCE (pure uint4 copies; pre-converted in K2) ----
  {
    const uint4* s1 = (const uint4*)w1b;                              // 1664
    for (int i = tid; i < 1664; i += 256) ((uint4*)w1B)[i] = s1[i];
    const uint4* s2 = (const uint4*)(w2b + (size_t)fam * 128 * 136);  // 2176
    for (int i = tid; i < 2176; i += 256) ((uint4*)w2B)[i] = s2[i];
    bias[tid] = (tid < 128) ? b1[tid] : b2[fam * 128 + (tid - 128)];
  }

  const int w = tid >> 6, lane = tid & 63;
  const int l15 = lane & 15, q = lane >> 4;
  const int mrow = 16 * w + l15;  // group row this lane supplies to A-frags

  for (int it = 0; it < 4; ++it) {
    const size_t g0 = (size_t)(cb + 256 * it) * 64;

    __syncthreads();  // HY free (prev fc2 done); weights visible on it==0

    // stage Y chunk: 768 uint4
    const uint4* ys = (const uint4*)(Y + g0 * 96);
    for (int i = tid; i < 768; i += 256) {
      const int r = i / 12, c = i - 12 * r;
      *(uint4*)&HY[r * 104 + 8 * c] = ys[i];
    }
    __syncthreads();

    // ---- fc1: K=96 ----
    bf8 ya[3];
#pragma unroll
    for (int ks = 0; ks < 3; ++ks)
      ya[ks] = *(const bf8*)&HY[mrow * 104 + 32 * ks + 8 * q];

    f32x4 acc1[8];
#pragma unroll
    for (int nt = 0; nt < 8; ++nt) {
      f32x4 a = {0.f, 0.f, 0.f, 0.f};
#pragma unroll
      for (int ks = 0; ks < 3; ++ks) {
        const bf8 wb = *(const bf8*)&w1B[(16 * nt + l15) * 104 + 32 * ks + 8 * q];
        a = __builtin_amdgcn_mfma_f32_16x16x32_bf16(ya[ks], wb, a, 0, 0, 0);
      }
      acc1[nt] = a;
    }
    __syncthreads();  // Yb fully consumed before Hb overwrites the union

    // epilogue 1: +b1, relu -> Hb[n][o1] bf16 (stride 136)
#pragma unroll
    for (int nt = 0; nt < 8; ++nt) {
#pragma unroll
      for (int r = 0; r < 4; ++r) {
        const int n = 16 * w + 4 * q + r;
        const int o = 16 * nt + l15;
        HY[n * 136 + o] = f2bf(fmaxf(acc1[nt][r] + bias[o], 0.0f));
      }
    }
    __syncthreads();

    // ---- fc2 half: K=128, 8 output tiles ----
    bf8 ha[4];
#pragma unroll
    for (int ks = 0; ks < 4; ++ks)
      ha[ks] = *(const bf8*)&HY[mrow * 136 + 32 * ks + 8 * q];

#pragma unroll 2
    for (int nt = 0; nt < 8; ++nt) {
      f32x4 a = {0.f, 0.f, 0.f, 0.f};
#pragma unroll
      for (int ks = 0; ks < 4; ++ks) {
        const bf8 wb = *(const bf8*)&w2B[(16 * nt + l15) * 136 + 32 * ks + 8 * q];
        a = __builtin_amdgcn_mfma_f32_16x16x32_bf16(ha[ks], wb, a, 0, 0, 0);
      }
#pragma unroll
      for (int r = 0; r < 4; ++r) {
        const int n = 16 * w + 4 * q + r;
        const int o = 16 * nt + l15;
        out[(g0 + n) * 256 + fam * 128 + o] = a[r] + bias[128 + o];
      }
    }
  }
}

// ---------------------------------------------------------------------------
extern "C" void kernel_launch(void* const* d_in, const int* in_sizes, int n_in,
                              void* d_out, int out_size, void* d_ws, size_t ws_size,
                              hipStream_t stream) {
  const float* x  = (const float*)d_in[0];
  const float* cw = (const float*)d_in[1];
  const float* cb = (const float*)d_in[2];
  const float* w1 = (const float*)d_in[3];
  const float* b1 = (const float*)d_in[4];
  const float* w2 = (const float*)d_in[5];
  const float* b2 = (const float*)d_in[6];
  float* outp = (float*)d_out;

  unsigned short* Abf = (unsigned short*)d_ws;          // 16*180*4096 = 23.6 MB
  unsigned short* Ybf = Abf + (size_t)16 * 180 * 4096;  // 65536*96    = 12.6 MB
  unsigned short* w1b = Ybf + (size_t)65536 * 96;       // 128*104
  unsigned short* w2b = w1b + 13312;                    // 256*136

  dwt2_kernel<<<512, 256, 0, stream>>>(x, Abf);
  conv_kernel<<<1071, 256, 0, stream>>>(Abf, cw, cb, Ybf, w1, w2, w1b, w2b);
  mlp_mfma_kernel<<<512, 256, 0, stream>>>(Ybf, w1b, w2b, b1, b2, outp);
}